// Round 7
// baseline (325.634 us; speedup 1.0000x reference)
//
#include <hip/hip_runtime.h>
#include <math.h>

// v7: register pressure shrunk BY DATA-STRUCTURE so the kernel fits under a
// 64-VGPR cap -> 8 waves/SIMD (32 waves/CU). v6 analysis: VGPR_Count is in
// 2-reg granules; v4-v6 all allocated to their 128-reg cap and spilled
// (WRITE_SIZE 70-131MB vs 33MB of true output). Dominant state was phase 1's
// w[14] (28 VGPR) + addresses + acc(16) + hoisted phase-2 reads.
//  - TH=4: w[10] = 20 regs, acc = 8, u/v = 8, misc ~15 -> ~55 live < 64
//  - __launch_bounds__(256,8): cap 64 (per-SIMD pool 512 regs)
//  - LDS 6*516*4 = 12384 B -> 8 blocks/CU co-resident (wave-limited)
//  - grid 4096 blocks = 2 clean rounds; XCD-chunked bijective swizzle
//  - 'nc' runtime channel count (prevents cross-channel unroll/hoist - v6 win)
//  - sumsq stored, sqrt folded into normalize (max monotone under sqrt)
#define HH 512
#define WW 512
#define TH 4           // output rows per block
#define NROWS 6        // blur rows held (TH + 2 sobel halo)
#define NLOAD 10       // img rows loaded (TH + 6)
#define VBW 516        // LDS row stride: img col x lives at idx x+2

// per-row fused horizontal-gaussian + sobel row terms for blur row r.
// u = p[x-1]-p[x+1], v = p[x-1]+2p[x]+p[x+1]
#define ROWCALC(r)                                                            \
    const int yb = ry0 - 1 + (r);                                             \
    const float rm = (yb >= 0 && yb < HH) ? 1.f : 0.f;                        \
    const float mA = haveA ? rm : 0.f;                                        \
    const float mC = haveC ? rm : 0.f;                                        \
    const float  Lf = haveA ? vb[r][c0 - 1] : 0.f;                            \
    const float2 A  = *(const float2*)&vb[r][c0];                             \
    const float2 Bv = *(const float2*)&vb[r][c0 + 2];                         \
    const float2 C  = *(const float2*)&vb[r][c0 + 4];                        \
    const float  Rf = haveC ? vb[r][c0 + 6] : 0.f;                            \
    const float blm1 = (g0*Lf   + g1*A.x  + g2*A.y  + g3*Bv.x + g4*Bv.y) * mA;\
    const float bl0  = (g0*A.x  + g1*A.y  + g2*Bv.x + g3*Bv.y + g4*C.x ) * rm;\
    const float bl1  = (g0*A.y  + g1*Bv.x + g2*Bv.y + g3*C.x  + g4*C.y ) * rm;\
    const float bl2  = (g0*Bv.x + g1*Bv.y + g2*C.x  + g3*C.y  + g4*Rf  ) * mC;\
    const float nu0 = blm1 - bl1;                                             \
    const float nv0 = blm1 + 2.f*bl0 + bl1;                                   \
    const float nu1 = bl0 - bl2;                                              \
    const float nv1 = bl0 + 2.f*bl1 + bl2;

#define ROWACC(r, o) {                                                        \
    ROWCALC(r)                                                                \
    const float gx0 = u0p0 + 2.f*u0p1 + nu0;                                  \
    const float gy0 = v0p0 - nv0;                                             \
    const float gx1 = u1p0 + 2.f*u1p1 + nu1;                                  \
    const float gy1 = v1p0 - nv1;                                             \
    acc0[o] += gx0*gx0 + gy0*gy0;                                             \
    acc1[o] += gx1*gx1 + gy1*gy1;                                             \
    u0p0 = u0p1; u0p1 = nu0;  v0p0 = v0p1; v0p1 = nv0;                        \
    u1p0 = u1p1; u1p1 = nu1;  v1p0 = v1p1; v1p1 = nv1; }

__global__ __launch_bounds__(256, 8)
void edge_fused_v7(const float* __restrict__ img,
                   const float* __restrict__ gauss,
                   float* __restrict__ out,
                   unsigned int* __restrict__ gmax,
                   int nc) {
    __shared__ float vb[NROWS][VBW];   // 6*516*4 = 12384 B

    const int tid = threadIdx.x;
    // XCD-chunked bijective swizzle (4096 blocks = 8 XCDs x 512)
    const int bid = (blockIdx.x & 7) * 512 + (blockIdx.x >> 3);
    const int strip = bid & 127;       // 512/4 = 128 strips per image
    const int b     = bid >> 7;        // batch index
    const int ry0 = strip * TH;
    const int c0  = tid * 2;           // this thread owns columns c0, c0+1

    const float g0 = gauss[0], g1 = gauss[1], g2 = gauss[2], g3 = gauss[3], g4 = gauss[4];

    const bool interior = (ry0 >= 3) && (ry0 + TH + 3 <= HH);  // strips 1..126
    const bool haveA = (tid != 0);
    const bool haveC = (tid != 255);
    const float2 Z = make_float2(0.f, 0.f);

    // one-time guard zeros: idx 0,1 (img cols -2,-1) and 514,515 (512,513).
    // phase1 writes idx 2..513 only -> these stay valid for all channels.
    if (tid < NROWS * 4) {
        const int r = tid >> 2, k = tid & 3;
        vb[r][(k < 2) ? k : 512 + k] = 0.f;
    }

    float acc0[TH], acc1[TH];
#pragma unroll
    for (int o = 0; o < TH; ++o) { acc0[o] = 0.f; acc1[o] = 0.f; }

    for (int c = 0; c < nc; ++c) {   // nc is RUNTIME -> cannot unroll
        const float* imgc = img + ((size_t)(b * 3 + c) * HH) * WW;

        // ---- phase 1: vertical gaussian -> LDS (cols c0,c0+1 as float2) ----
        float2 w[NLOAD];               // 20 VGPR
        if (interior) {
#pragma unroll
            for (int i = 0; i < NLOAD; ++i)
                w[i] = *(const float2*)(imgc + (size_t)(ry0 - 3 + i) * WW + c0);
        } else {
#pragma unroll
            for (int i = 0; i < NLOAD; ++i) {
                const int y = ry0 - 3 + i;
                w[i] = (y >= 0 && y < HH)
                     ? *(const float2*)(imgc + (size_t)y * WW + c0)
                     : Z;
            }
        }
#pragma unroll
        for (int r = 0; r < NROWS; ++r) {
            float2 s;
            s.x = g0*w[r].x + g1*w[r+1].x + g2*w[r+2].x + g3*w[r+3].x + g4*w[r+4].x;
            s.y = g0*w[r].y + g1*w[r+1].y + g2*w[r+2].y + g3*w[r+3].y + g4*w[r+4].y;
            *(float2*)&vb[r][c0 + 2] = s;   // idx c0+2 (even, 8B aligned)
        }
        __syncthreads();

        // ---- phase 2: fused horizontal gaussian + sobel over 6 blur rows ----
        float u0p0, u0p1, v0p0, v0p1, u1p0, u1p1, v1p0, v1p1;
        { ROWCALC(0) u0p0 = nu0; v0p0 = nv0; u1p0 = nu1; v1p0 = nv1; }
        { ROWCALC(1) u0p1 = nu0; v0p1 = nv0; u1p1 = nu1; v1p1 = nv1; }
        ROWACC(2, 0)
        ROWACC(3, 1)
        ROWACC(4, 2)
        ROWACC(5, 3)
        __syncthreads();   // protect vb before next channel's phase 1
    }

    // ---- epilogue: store SUMSQ (sqrt deferred), block max -> atomicMax ----
    float m = 0.f;
#pragma unroll
    for (int o = 0; o < TH; ++o) {
        float2 v; v.x = acc0[o]; v.y = acc1[o];
        *(float2*)(out + ((size_t)b * HH + (ry0 + o)) * WW + c0) = v;
        m = fmaxf(m, fmaxf(v.x, v.y));
    }
#pragma unroll
    for (int off = 32; off > 0; off >>= 1)
        m = fmaxf(m, __shfl_xor(m, off, 64));
    if ((tid & 63) == 0) vb[0][tid >> 6] = m;   // vb reused as scratch
    __syncthreads();
    if (tid == 0) {
        const float bm = fmaxf(fmaxf(vb[0][0], vb[0][1]), fmaxf(vb[0][2], vb[0][3]));
        // values non-negative: float bits monotone as unsigned
        atomicMax(gmax, __float_as_uint(bm));
    }
}

__global__ __launch_bounds__(256)
void normalize_v7(float* __restrict__ out,
                  const unsigned int* __restrict__ gmax,
                  int n4) {
    // out holds sumsq; gmax holds max(sumsq). sqrt(a)/sqrt(mx) = sqrt(a*inv)
    const float inv = 1.0f / __uint_as_float(*gmax);
    float4* o4 = (float4*)out;
    const int stride = gridDim.x * blockDim.x;
    for (int i = blockIdx.x * blockDim.x + threadIdx.x; i < n4; i += stride) {
        float4 v = o4[i];
        v.x = sqrtf(v.x * inv);
        v.y = sqrtf(v.y * inv);
        v.z = sqrtf(v.z * inv);
        v.w = sqrtf(v.w * inv);
        o4[i] = v;
    }
}

extern "C" void kernel_launch(void* const* d_in, const int* in_sizes, int n_in,
                              void* d_out, int out_size, void* d_ws, size_t ws_size,
                              hipStream_t stream) {
    const float* img   = (const float*)d_in[0];
    const float* gauss = (const float*)d_in[1];
    float* out = (float*)d_out;

    unsigned int* gmax = (unsigned int*)d_ws;
    hipMemsetAsync(gmax, 0, sizeof(unsigned int), stream);   // ws re-poisoned each launch

    const int B = 32;
    const int blocks = B * (HH / TH);   // 32 * 128 = 4096
    edge_fused_v7<<<blocks, 256, 0, stream>>>(img, gauss, out, gmax, 3);

    const int n4 = out_size / 4;        // 2,097,152 float4s
    normalize_v7<<<4096, 256, 0, stream>>>(out, gmax, n4);
}